// Round 3
// baseline (284.944 us; speedup 1.0000x reference)
//
#include <hip/hip_runtime.h>
#include <math.h>

// Problem constants (x: [8192, 512] fp32, K=5, eps=1e-8, scalar fp32 loss)
#define NROWS 8192
#define DIM   512
#define KNN   5
#define EPSV  1e-8f

// GEMM tiling: 128x128 block tile, BK=32, 4 waves (2x2), each wave 4x4 of 16x16x32 MFMA
#define BM 128
#define BN 128
#define BK 32
#define NSPLIT 16              // j-range splits per row-block -> 64*16 = 1024 blocks
#define JT_PER_SPLIT ((NROWS / BN) / NSPLIT)   // 4

typedef __attribute__((ext_vector_type(8))) _Float16 f16x8;
typedef __attribute__((ext_vector_type(4))) _Float16 f16x4;
typedef __attribute__((ext_vector_type(4))) float    f32x4;

// async global->LDS, 16B per lane (LDS side must be wave-uniform base + lane*16)
__device__ __forceinline__ void gload16(const _Float16* g, _Float16* l) {
    __builtin_amdgcn_global_load_lds(
        (const __attribute__((address_space(1))) void*)g,
        (__attribute__((address_space(3))) void*)l, 16, 0, 0);
}

__device__ __forceinline__ void cmpswap(float& a, float& b) {
    const float hi = fmaxf(a, b), lo = fminf(a, b);
    a = hi; b = lo;
}

// merge two sorted-descending 5-lists -> top-5 (into a).
// c[k] = max(a[k], b[k], max_{i+j=k-1} min(a[i], b[j]))
__device__ __forceinline__ void merge5(float a[KNN], const float b[KNN]) {
    const float c0 = fmaxf(a[0], b[0]);
    const float c1 = fmaxf(fmaxf(a[1], b[1]), fminf(a[0], b[0]));
    const float c2 = fmaxf(fmaxf(a[2], b[2]),
                           fmaxf(fminf(a[0], b[1]), fminf(a[1], b[0])));
    const float c3 = fmaxf(fmaxf(a[3], b[3]),
                           fmaxf(fminf(a[0], b[2]),
                                 fmaxf(fminf(a[1], b[1]), fminf(a[2], b[0]))));
    const float c4 = fmaxf(fmaxf(a[4], b[4]),
                           fmaxf(fmaxf(fminf(a[0], b[3]), fminf(a[1], b[2])),
                                 fmaxf(fminf(a[2], b[1]), fminf(a[3], b[0]))));
    a[0] = c0; a[1] = c1; a[2] = c2; a[3] = c3; a[4] = c4;
}

__device__ __forceinline__ void top5_insert(float v, float& t0, float& t1,
                                            float& t2, float& t3, float& t4) {
    if (v > t4) {
        if (v > t2) {
            if (v > t1) {
                if (v > t0) { t4 = t3; t3 = t2; t2 = t1; t1 = t0; t0 = v; }
                else        { t4 = t3; t3 = t2; t2 = t1; t1 = v; }
            } else          { t4 = t3; t3 = t2; t2 = v; }
        } else {
            if (v > t3)     { t4 = t3; t3 = v; }
            else            { t4 = v; }
        }
    }
}

// ---------------------------------------------------------------------------
// Kernel 1: row-normalize x (fp32) -> xn (f16). One WAVE per row (no barriers).
// Also zeroes the per-row threshold array and the output accumulator.
// ---------------------------------------------------------------------------
__global__ __launch_bounds__(256) void norm_kernel(const float* __restrict__ x,
                                                   _Float16* __restrict__ xnh,
                                                   unsigned* __restrict__ thr,
                                                   float* __restrict__ out) {
    const int wv = threadIdx.x >> 6, lane = threadIdx.x & 63;
    const int row = blockIdx.x * 4 + wv;
    const float4* xr = (const float4*)(x + (size_t)row * DIM) + lane;
    const float4 a = xr[0];
    const float4 b = xr[64];
    float s = a.x * a.x + a.y * a.y + a.z * a.z + a.w * a.w
            + b.x * b.x + b.y * b.y + b.z * b.z + b.w * b.w;
    #pragma unroll
    for (int off = 1; off < 64; off <<= 1) s += __shfl_xor(s, off, 64);
    const float inv = 1.0f / sqrtf(s);
    const f16x4 ha = { (_Float16)(a.x * inv), (_Float16)(a.y * inv),
                       (_Float16)(a.z * inv), (_Float16)(a.w * inv) };
    const f16x4 hb = { (_Float16)(b.x * inv), (_Float16)(b.y * inv),
                       (_Float16)(b.z * inv), (_Float16)(b.w * inv) };
    *(f16x4*)(xnh + (size_t)row * DIM + lane * 4)       = ha;
    *(f16x4*)(xnh + (size_t)row * DIM + 256 + lane * 4) = hb;

    const int g = blockIdx.x * 256 + threadIdx.x;
    if (g < NROWS) thr[g] = 0u;              // decodes to threshold -2
    if (g == NROWS) *out = 0.f;
}

// ---------------------------------------------------------------------------
// Kernel 2: fused Gram-tile GEMM + in-register per-row top-5 with globally
// shared per-row pruning thresholds.
// thr[row] holds uint bits of (t4_lower_bound + 2.0) — monotone for positives;
// any block's local 5th-best is a valid lower bound of the global 5th-best,
// so values <= it can never enter the final top-5 (sound pruning).
// LDS staging is chunk-XOR-swizzled to kill ds_read_b128 bank conflicts
// (global_load_lds forbids padding; the global SOURCE chunk is free to pick).
// ---------------------------------------------------------------------------
__global__ __launch_bounds__(256) void dots_top5_kernel(const _Float16* __restrict__ xnh,
                                                        unsigned* __restrict__ thr,
                                                        float* __restrict__ part) {
    __shared__ __align__(16) _Float16 As[BM * BK];   // 8 KB
    __shared__ __align__(16) _Float16 Bs[BN * BK];   // 8 KB
    __shared__ float mbuf[2 * 64 * KNN];             // 2.5 KB cross-wave merge

    const int tid    = threadIdx.x;
    const int lane   = tid & 63;
    const int wv     = tid >> 6;
    const int wm     = wv >> 1;          // wave row half (0..1)
    const int wn     = wv & 1;           // wave col half (0..1)
    const int m_lane = lane & 15;        // MFMA: m (A) / n (B) / col (C)
    const int quad   = lane >> 4;        // MFMA: k-chunk (A,B) / row-group (C)

    const int rowblk = blockIdx.x >> 4;  // 0..63
    const int split  = blockIdx.x & 15;  // 0..15
    const int i0     = rowblk * BM;

    // lane (quad, m_lane) owns row rowlocal for (m = m_lane>>2, i = m_lane&3)
    const int rowlocal = (m_lane >> 2) * 16 + quad * 4 + (m_lane & 3);
    const int myrow    = i0 + wm * 64 + rowlocal;
    // swizzled k-chunk slot for fragment reads (involution of staging swizzle)
    const int kkA = quad ^ (m_lane & 3) ^ ((m_lane >> 2) & 3);

    float t[KNN];
    #pragma unroll
    for (int k = 0; k < KNN; ++k) t[k] = -2.f;

    for (int jj = 0; jj < JT_PER_SPLIT; ++jj) {
        const int jt = split * JT_PER_SPLIT + jj;
        const int j0 = jt * BN;

        // coherent read of the shared per-row threshold (atomic -> L2-fresh)
        float gthr = __uint_as_float(atomicMax(thr + myrow, 0u)) - 2.0f;

        f32x4 acc[4][4];
        #pragma unroll
        for (int m = 0; m < 4; ++m)
            #pragma unroll
            for (int n = 0; n < 4; ++n)
                acc[m][n] = (f32x4){0.f, 0.f, 0.f, 0.f};

        for (int ks = 0; ks < DIM / BK; ++ks) {
            const int k0 = ks * BK;
            // stage A,B tiles via async global->LDS. Slot s=(r,kk) receives
            // global chunk kk ^ (r&3) ^ ((r>>2)&3)  (bank-conflict swizzle).
            #pragma unroll
            for (int q = 0; q < 2; ++q) {
                const int s  = tid + q * 256;
                const int r  = s >> 2;
                const int kk = (s & 3) ^ (r & 3) ^ ((r >> 2) & 3);
                gload16(xnh + (size_t)(i0 + r) * DIM + k0 + kk * 8, As + s * 8);
                gload16(xnh + (size_t)(j0 + r) * DIM + k0 + kk * 8, Bs + s * 8);
            }
            __syncthreads();

            f16x8 af[4], bf[4];
            #pragma unroll
            for (int m = 0; m < 4; ++m)
                af[m] = *(const f16x8*)(As + (wm * 64 + m * 16 + m_lane) * BK + kkA * 8);
            #pragma unroll
            for (int n = 0; n < 4; ++n)
                bf[n] = *(const f16x8*)(Bs + (wn * 64 + n * 16 + m_lane) * BK + kkA * 8);
            #pragma unroll
            for (int m = 0; m < 4; ++m)
                #pragma unroll
                for (int n = 0; n < 4; ++n)
                    acc[m][n] = __builtin_amdgcn_mfma_f32_16x16x32_f16(af[m], bf[n], acc[m][n], 0, 0, 0);
            __syncthreads();
        }

        // diagonal mask: self-dot only when jt==rowblk && wm==wn && m==n.
        const bool diag = (jt == rowblk) && (wm == wn);
        #pragma unroll
        for (int m = 0; m < 4; ++m)
            #pragma unroll
            for (int i = 0; i < 4; ++i)
                acc[m][m][i] = (diag && (quad * 4 + i) == m_lane) ? -2.f : acc[m][m][i];

        // selection: per (m,i), each quad's 16 lanes hold the 64 cols of one row.
        #pragma unroll
        for (int m = 0; m < 4; ++m) {
            #pragma unroll
            for (int i = 0; i < 4; ++i) {
                const float v0 = acc[m][0][i], v1 = acc[m][1][i];
                const float v2 = acc[m][2][i], v3 = acc[m][3][i];
                const float lmax = fmaxf(fmaxf(v0, v1), fmaxf(v2, v3));
                const int owner = m * 4 + i;      // m_lane index owning this row
                const float cthr = fmaxf(t[KNN - 1], gthr);
                const float thrb = __shfl(cthr, quad * 16 + owner, 64);
                if (__any(lmax > thrb)) {
                    float c[KNN];
                    c[0] = v0; c[1] = v1; c[2] = v2; c[3] = v3; c[4] = -2.f;
                    cmpswap(c[0], c[1]); cmpswap(c[2], c[3]);
                    cmpswap(c[0], c[2]); cmpswap(c[1], c[3]);
                    cmpswap(c[1], c[2]);
                    #pragma unroll
                    for (int d = 1; d < 16; d <<= 1) {
                        float b[KNN];
                        #pragma unroll
                        for (int k = 0; k < KNN; ++k) b[k] = __shfl_xor(c[k], d, 64);
                        merge5(c, b);
                    }
                    float nt[KNN];
                    #pragma unroll
                    for (int k = 0; k < KNN; ++k) nt[k] = t[k];
                    merge5(nt, c);
                    const bool is_owner = (m_lane == owner);
                    #pragma unroll
                    for (int k = 0; k < KNN; ++k) t[k] = is_owner ? nt[k] : t[k];
                    if (is_owner && t[KNN - 1] > gthr) {
                        atomicMax(thr + myrow, __float_as_uint(t[KNN - 1] + 2.0f));
                        gthr = t[KNN - 1];
                    }
                }
            }
        }
    }

    // cross-wave (wn) merge: both col-half waves hold the same 64 rows.
    __syncthreads();
    if (wn == 1) {
        #pragma unroll
        for (int k = 0; k < KNN; ++k)
            mbuf[(wm * 64 + rowlocal) * KNN + k] = t[k];
    }
    __syncthreads();
    if (wn == 0) {
        float b[KNN];
        #pragma unroll
        for (int k = 0; k < KNN; ++k) b[k] = mbuf[(wm * 64 + rowlocal) * KNN + k];
        merge5(t, b);
        float* p = part + (size_t)myrow * (NSPLIT * KNN) + split * KNN;
        #pragma unroll
        for (int k = 0; k < KNN; ++k) p[k] = t[k];
    }
}

// ---------------------------------------------------------------------------
// Kernel 3: merge the NSPLIT per-split top-5 lists per row, loss, reduce.
// ---------------------------------------------------------------------------
__global__ __launch_bounds__(256) void merge_kernel(const float* __restrict__ part,
                                                    float* __restrict__ out) {
    const int row = blockIdx.x * 256 + threadIdx.x;
    const float* p = part + (size_t)row * (NSPLIT * KNN);
    float t0 = -2.f, t1 = -2.f, t2 = -2.f, t3 = -2.f, t4 = -2.f;
    #pragma unroll
    for (int k = 0; k < NSPLIT * KNN; ++k)
        top5_insert(p[k], t0, t1, t2, t3, t4);

    // unit vectors: ||xi - xj|| = sqrt(2 - 2*dot)
    float s = 0.f;
    s += sqrtf(fmaxf(2.f - 2.f * t0, 0.f));
    s += sqrtf(fmaxf(2.f - 2.f * t1, 0.f));
    s += sqrtf(fmaxf(2.f - 2.f * t2, 0.f));
    s += sqrtf(fmaxf(2.f - 2.f * t3, 0.f));
    s += sqrtf(fmaxf(2.f - 2.f * t4, 0.f));
    const float mean_rho = s * (1.f / KNN);
    float val = logf(mean_rho + EPSV);

    #pragma unroll
    for (int off = 32; off > 0; off >>= 1) val += __shfl_down(val, off, 64);
    __shared__ float red[4];
    const int lane = threadIdx.x & 63, wv = threadIdx.x >> 6;
    if (lane == 0) red[wv] = val;
    __syncthreads();
    if (threadIdx.x == 0) {
        const float blocksum = red[0] + red[1] + red[2] + red[3];
        atomicAdd(out, -blocksum / (float)NROWS);
    }
}

// ---------------------------------------------------------------------------
extern "C" void kernel_launch(void* const* d_in, const int* in_sizes, int n_in,
                              void* d_out, int out_size, void* d_ws, size_t ws_size,
                              hipStream_t stream) {
    const float* x = (const float*)d_in[0];
    float* out = (float*)d_out;
    char* ws = (char*)d_ws;

    _Float16* xnh = (_Float16*)ws;                                        // 8 MB
    float* part = (float*)(ws + (size_t)NROWS * DIM * sizeof(_Float16));  // 2.62 MB
    unsigned* thr = (unsigned*)(ws + (size_t)NROWS * DIM * sizeof(_Float16)
                                + (size_t)NROWS * NSPLIT * KNN * sizeof(float)); // 32 KB

    norm_kernel<<<NROWS / 4, 256, 0, stream>>>(x, xnh, thr, out);
    dots_top5_kernel<<<(NROWS / BM) * NSPLIT, 256, 0, stream>>>(xnh, thr, part);
    merge_kernel<<<NROWS / 256, 256, 0, stream>>>(part, out);
}

// Round 4
// 238.773 us; speedup vs baseline: 1.1934x; 1.1934x over previous
//
#include <hip/hip_runtime.h>
#include <math.h>

// Problem constants (x: [8192, 512] fp32, K=5, eps=1e-8, scalar fp32 loss)
#define NROWS 8192
#define DIM   512
#define KNN   5
#define EPSV  1e-8f

// GEMM tiling: 128x128 block tile, BK=32, 4 waves (2x2), each wave 4x4 of 16x16x32 MFMA
#define BM 128
#define BN 128
#define BK 32
#define NSPLIT 16              // 64 row-blocks x 16 splits = 1024 blocks
#define JT_PER_SPLIT 4
#define NT64 (NROWS / 64)      // 128 64-col tiles per row

typedef __attribute__((ext_vector_type(8))) _Float16 f16x8;
typedef __attribute__((ext_vector_type(4))) float    f32x4;

// async global->LDS, 16B per lane (LDS dest must be wave-uniform base + lane*16)
__device__ __forceinline__ void gload16(const _Float16* g, _Float16* l) {
    __builtin_amdgcn_global_load_lds(
        (const __attribute__((address_space(1))) void*)g,
        (__attribute__((address_space(3))) void*)l, 16, 0, 0);
}

__device__ __forceinline__ void cmpswap(float& a, float& b) {
    const float hi = fmaxf(a, b), lo = fminf(a, b);
    a = hi; b = lo;
}

// merge two sorted-descending 5-lists -> top-5 (into a).
// c[k] = max(a[k], b[k], max_{i+j=k-1} min(a[i], b[j]))
__device__ __forceinline__ void merge5(float a[KNN], const float b[KNN]) {
    const float c0 = fmaxf(a[0], b[0]);
    const float c1 = fmaxf(fmaxf(a[1], b[1]), fminf(a[0], b[0]));
    const float c2 = fmaxf(fmaxf(a[2], b[2]),
                           fmaxf(fminf(a[0], b[1]), fminf(a[1], b[0])));
    const float c3 = fmaxf(fmaxf(a[3], b[3]),
                           fmaxf(fminf(a[0], b[2]),
                                 fmaxf(fminf(a[1], b[1]), fminf(a[2], b[0]))));
    const float c4 = fmaxf(fmaxf(a[4], b[4]),
                           fmaxf(fmaxf(fminf(a[0], b[3]), fminf(a[1], b[2])),
                                 fmaxf(fminf(a[2], b[1]), fminf(a[3], b[0]))));
    a[0] = c0; a[1] = c1; a[2] = c2; a[3] = c3; a[4] = c4;
}

// ---------------------------------------------------------------------------
// Kernel 1: row-normalize x (fp32) -> xn (f16). One WAVE per row, 16B stores.
// ---------------------------------------------------------------------------
__global__ __launch_bounds__(256) void norm_kernel(const float* __restrict__ x,
                                                   _Float16* __restrict__ xnh,
                                                   float* __restrict__ out) {
    const int wv = threadIdx.x >> 6, lane = threadIdx.x & 63;
    const int row = blockIdx.x * 4 + wv;
    const float4* xr = (const float4*)(x + (size_t)row * DIM) + lane * 2;
    const float4 a = xr[0];
    const float4 b = xr[1];
    float s = a.x * a.x + a.y * a.y + a.z * a.z + a.w * a.w
            + b.x * b.x + b.y * b.y + b.z * b.z + b.w * b.w;
    #pragma unroll
    for (int off = 1; off < 64; off <<= 1) s += __shfl_xor(s, off, 64);
    const float inv = 1.0f / sqrtf(s);
    const f16x8 h = { (_Float16)(a.x * inv), (_Float16)(a.y * inv),
                      (_Float16)(a.z * inv), (_Float16)(a.w * inv),
                      (_Float16)(b.x * inv), (_Float16)(b.y * inv),
                      (_Float16)(b.z * inv), (_Float16)(b.w * inv) };
    *(f16x8*)(xnh + (size_t)row * DIM + lane * 8) = h;

    if (blockIdx.x == 0 && threadIdx.x == 0) *out = 0.f;
}

// ---------------------------------------------------------------------------
// Kernel 2: Gram-tile GEMM + per-(row, 64-col-tile) TOP-3 (no running top-5,
// no cross-wave merge, no atomics). M3 layout: [row][jt2][3] floats.
// Selection per (m,i): lane-local sort4 -> top-3, 4-step shfl_xor butterfly
// with a 9-op merge3 — ~61 VALU ops/group vs ~170 for the old top-5 path.
// ---------------------------------------------------------------------------
__global__ __launch_bounds__(256) void dots_top3_kernel(const _Float16* __restrict__ xnh,
                                                        float* __restrict__ M3) {
    __shared__ __align__(16) _Float16 As[BM * BK];   // 8 KB
    __shared__ __align__(16) _Float16 Bs[BN * BK];   // 8 KB

    const int tid    = threadIdx.x;
    const int lane   = tid & 63;
    const int wv     = tid >> 6;
    const int wm     = wv >> 1;          // wave row half (0..1)
    const int wn     = wv & 1;           // wave col half (0..1)
    const int m_lane = lane & 15;        // MFMA: m (A) / n (B) / col (C)
    const int quad   = lane >> 4;        // MFMA: k-chunk (A,B) / row-group (C)

    const int rowblk = blockIdx.x >> 4;  // 0..63
    const int split  = blockIdx.x & 15;  // 0..15
    const int i0     = rowblk * BM;

    // lane (quad, m_lane) owns row rowlocal (its (m,i) = (m_lane>>2, m_lane&3))
    const int rowlocal = (m_lane >> 2) * 16 + quad * 4 + (m_lane & 3);
    const int myrow    = i0 + wm * 64 + rowlocal;

    for (int jj = 0; jj < JT_PER_SPLIT; ++jj) {
        const int jt = split * JT_PER_SPLIT + jj;   // 128-col tile 0..63
        const int j0 = jt * BN;

        f32x4 acc[4][4];
        #pragma unroll
        for (int m = 0; m < 4; ++m)
            #pragma unroll
            for (int n = 0; n < 4; ++n)
                acc[m][n] = (f32x4){0.f, 0.f, 0.f, 0.f};

        for (int ks = 0; ks < DIM / BK; ++ks) {
            const int k0 = ks * BK;
            #pragma unroll
            for (int q = 0; q < 2; ++q) {
                const int s  = tid + q * 256;
                const int r  = s >> 2;
                const int kk = s & 3;
                gload16(xnh + (size_t)(i0 + r) * DIM + k0 + kk * 8, As + s * 8);
                gload16(xnh + (size_t)(j0 + r) * DIM + k0 + kk * 8, Bs + s * 8);
            }
            __syncthreads();

            f16x8 af[4], bf[4];
            #pragma unroll
            for (int m = 0; m < 4; ++m)
                af[m] = *(const f16x8*)(As + (wm * 64 + m * 16 + m_lane) * BK + quad * 8);
            #pragma unroll
            for (int n = 0; n < 4; ++n)
                bf[n] = *(const f16x8*)(Bs + (wn * 64 + n * 16 + m_lane) * BK + quad * 8);
            #pragma unroll
            for (int m = 0; m < 4; ++m)
                #pragma unroll
                for (int n = 0; n < 4; ++n)
                    acc[m][n] = __builtin_amdgcn_mfma_f32_16x16x32_f16(af[m], bf[n], acc[m][n], 0, 0, 0);
            __syncthreads();
        }

        // diagonal mask: self-dot only when jt==rowblk && wm==wn && m==n.
        const bool diag = (jt == rowblk) && (wm == wn);
        #pragma unroll
        for (int m = 0; m < 4; ++m)
            #pragma unroll
            for (int i = 0; i < 4; ++i)
                acc[m][m][i] = (diag && (quad * 4 + i) == m_lane) ? -2.f : acc[m][m][i];

        // per (m,i): top-3 of the 64 cols of row (wm*64 + m*16 + quad*4 + i)
        float g1 = -2.f, g2 = -2.f, g3 = -2.f;
        #pragma unroll
        for (int m = 0; m < 4; ++m) {
            #pragma unroll
            for (int i = 0; i < 4; ++i) {
                float v0 = acc[m][0][i], v1 = acc[m][1][i];
                float v2 = acc[m][2][i], v3 = acc[m][3][i];
                cmpswap(v0, v1); cmpswap(v2, v3);
                cmpswap(v0, v2); cmpswap(v1, v3);
                cmpswap(v1, v2);                     // v0>=v1>=v2 (>=v3, dropped)
                float a1 = v0, a2 = v1, a3 = v2;
                #pragma unroll
                for (int d = 1; d < 16; d <<= 1) {
                    const float b1 = __shfl_xor(a1, d, 64);
                    const float b2 = __shfl_xor(a2, d, 64);
                    const float b3 = __shfl_xor(a3, d, 64);
                    const float n1 = fmaxf(a1, b1);
                    const float n2 = fmaxf(fminf(a1, b1), fmaxf(a2, b2));
                    const float n3 = fmaxf(fmaxf(a3, b3),
                                           fmaxf(fminf(a1, b2), fminf(a2, b1)));
                    a1 = n1; a2 = n2; a3 = n3;
                }
                const bool own = (m_lane == m * 4 + i);
                g1 = own ? a1 : g1; g2 = own ? a2 : g2; g3 = own ? a3 : g3;
            }
        }

        // store this 64-col tile's top-3 for my row (wn picks the half-tile)
        const int jt2 = jt * 2 + wn;
        float* p = M3 + ((size_t)myrow * NT64 + jt2) * 3;
        p[0] = g1; p[1] = g2; p[2] = g3;
    }
}

// ---------------------------------------------------------------------------
// Kernel 3: exact top-5 per row from the 128 stored triples + loss.
// One wave per row. Lane l holds tiles 2l, 2l+1. Pool ⊆ full set ⇒ pool's
// 5th-best t[4] ≤ true 5th-best; a tile can hide a missed top-5 value only if
// its stored 3rd ≥ t[4] — those (rare) tiles are exactly recomputed.
// ---------------------------------------------------------------------------
__global__ __launch_bounds__(256) void select_loss_kernel(const _Float16* __restrict__ xnh,
                                                          const float* __restrict__ M3,
                                                          float* __restrict__ out) {
    const int wv = threadIdx.x >> 6, lane = threadIdx.x & 63;
    const int row = blockIdx.x * 4 + wv;
    const float* p = M3 + (size_t)row * NT64 * 3 + lane * 6;
    float a[3], b[3];
    a[0] = p[0]; a[1] = p[1]; a[2] = p[2];
    b[0] = p[3]; b[1] = p[4]; b[2] = p[5];

    float t[KNN];
    {
        float c[KNN] = { a[0], a[1], a[2], -2.f, -2.f };
        const float bb[KNN] = { b[0], b[1], b[2], -2.f, -2.f };
        merge5(c, bb);
        #pragma unroll
        for (int d = 1; d < 64; d <<= 1) {
            float o[KNN];
            #pragma unroll
            for (int k = 0; k < KNN; ++k) o[k] = __shfl_xor(c[k], d, 64);
            merge5(c, o);
        }
        #pragma unroll
        for (int k = 0; k < KNN; ++k) t[k] = c[k];
    }

    // flag tiles whose stored 3rd could hide a missed top-5 value
    const unsigned long long ba = __ballot(a[2] >= t[4]);
    const unsigned long long bb_ = __ballot(b[2] >= t[4]);
    if (ba | bb_) {
        // rebuild the pool top-5 excluding flagged tiles
        const bool fA = (ba >> lane) & 1ull, fB = (bb_ >> lane) & 1ull;
        float c[KNN] = { fA ? -2.f : a[0], fA ? -2.f : a[1], fA ? -2.f : a[2],
                         -2.f, -2.f };
        const float b5[KNN] = { fB ? -2.f : b[0], fB ? -2.f : b[1],
                                fB ? -2.f : b[2], -2.f, -2.f };
        merge5(c, b5);
        #pragma unroll
        for (int d = 1; d < 64; d <<= 1) {
            float o[KNN];
            #pragma unroll
            for (int k = 0; k < KNN; ++k) o[k] = __shfl_xor(c[k], d, 64);
            merge5(c, o);
        }
        #pragma unroll
        for (int k = 0; k < KNN; ++k) t[k] = c[k];

        // exactly recompute each flagged 64-col tile (whole wave, 1 col/lane)
        unsigned long long fl[2] = { ba, bb_ };
        #pragma unroll
        for (int h = 0; h < 2; ++h) {
            unsigned long long m = fl[h];
            while (m) {
                const int l = __ffsll((long long)m) - 1;
                m &= m - 1;
                const int jt2 = 2 * l + h;
                const int col = jt2 * 64 + lane;
                const _Float16* rp = xnh + (size_t)row * DIM;
                const _Float16* cp = xnh + (size_t)col * DIM;
                float d = 0.f;
                for (int k8 = 0; k8 < DIM / 8; ++k8) {
                    const f16x8 rv = *(const f16x8*)(rp + k8 * 8);
                    const f16x8 cv = *(const f16x8*)(cp + k8 * 8);
                    #pragma unroll
                    for (int e = 0; e < 8; ++e)
                        d += (float)rv[e] * (float)cv[e];
                }
                if (col == row) d = -2.f;
                float c2[KNN] = { d, -2.f, -2.f, -2.f, -2.f };
                #pragma unroll
                for (int dd = 1; dd < 64; dd <<= 1) {
                    float o[KNN];
                    #pragma unroll
                    for (int k = 0; k < KNN; ++k) o[k] = __shfl_xor(c2[k], dd, 64);
                    merge5(c2, o);
                }
                merge5(t, c2);
            }
        }
    }

    // loss: unit vectors -> dist_k = sqrt(2 - 2*dot_k)
    float s = 0.f;
    #pragma unroll
    for (int k = 0; k < KNN; ++k) s += sqrtf(fmaxf(2.f - 2.f * t[k], 0.f));
    const float val = logf(s * (1.f / KNN) + EPSV);

    __shared__ float red[4];
    if (lane == 0) red[wv] = val;
    __syncthreads();
    if (threadIdx.x == 0) {
        const float blocksum = red[0] + red[1] + red[2] + red[3];
        atomicAdd(out, -blocksum / (float)NROWS);
    }
}

// ---------------------------------------------------------------------------
extern "C" void kernel_launch(void* const* d_in, const int* in_sizes, int n_in,
                              void* d_out, int out_size, void* d_ws, size_t ws_size,
                              hipStream_t stream) {
    const float* x = (const float*)d_in[0];
    float* out = (float*)d_out;
    char* ws = (char*)d_ws;

    _Float16* xnh = (_Float16*)ws;                                  // 8 MB
    float* M3 = (float*)(ws + (size_t)NROWS * DIM * sizeof(_Float16)); // 12.6 MB

    norm_kernel<<<NROWS / 4, 256, 0, stream>>>(x, xnh, out);
    dots_top3_kernel<<<(NROWS / BM) * NSPLIT, 256, 0, stream>>>(xnh, M3);
    select_loss_kernel<<<NROWS / 4, 256, 0, stream>>>(xnh, M3, out);
}

// Round 5
// 181.267 us; speedup vs baseline: 1.5720x; 1.3172x over previous
//
#include <hip/hip_runtime.h>
#include <math.h>

// Problem constants (x: [8192, 512] fp32, K=5, eps=1e-8, scalar fp32 loss)
#define NROWS 8192
#define DIM   512
#define KNN   5
#define EPSV  1e-8f

// GEMM tiling: 128x128 block tile, BK=32, 4 waves (2x2), each wave 4x4 of 16x16x32 MFMA
#define BM 128
#define BN 128
#define BK 32
#define NT (NROWS / BM)        // 64 tile indices per dimension
#define NT64 (NROWS / 64)      // 128 64-col tiles per row

typedef __attribute__((ext_vector_type(8))) _Float16 f16x8;
typedef __attribute__((ext_vector_type(4))) float    f32x4;

// async global->LDS, 16B per lane (LDS dest must be wave-uniform base + lane*16)
__device__ __forceinline__ void gload16(const _Float16* g, _Float16* l) {
    __builtin_amdgcn_global_load_lds(
        (const __attribute__((address_space(1))) void*)g,
        (__attribute__((address_space(3))) void*)l, 16, 0, 0);
}

__device__ __forceinline__ void cmpswap(float& a, float& b) {
    const float hi = fmaxf(a, b), lo = fminf(a, b);
    a = hi; b = lo;
}

// merge two sorted-descending 5-lists -> top-5 (into a).
__device__ __forceinline__ void merge5(float a[KNN], const float b[KNN]) {
    const float c0 = fmaxf(a[0], b[0]);
    const float c1 = fmaxf(fmaxf(a[1], b[1]), fminf(a[0], b[0]));
    const float c2 = fmaxf(fmaxf(a[2], b[2]),
                           fmaxf(fminf(a[0], b[1]), fminf(a[1], b[0])));
    const float c3 = fmaxf(fmaxf(a[3], b[3]),
                           fmaxf(fminf(a[0], b[2]),
                                 fmaxf(fminf(a[1], b[1]), fminf(a[2], b[0]))));
    const float c4 = fmaxf(fmaxf(a[4], b[4]),
                           fmaxf(fmaxf(fminf(a[0], b[3]), fminf(a[1], b[2])),
                                 fmaxf(fminf(a[2], b[1]), fminf(a[3], b[0]))));
    a[0] = c0; a[1] = c1; a[2] = c2; a[3] = c3; a[4] = c4;
}

// ---------------------------------------------------------------------------
// Kernel 1: row-normalize x (fp32) -> xn (f16). One WAVE per row, 16B stores.
// ---------------------------------------------------------------------------
__global__ __launch_bounds__(256) void norm_kernel(const float* __restrict__ x,
                                                   _Float16* __restrict__ xnh,
                                                   float* __restrict__ out) {
    const int wv = threadIdx.x >> 6, lane = threadIdx.x & 63;
    const int row = blockIdx.x * 4 + wv;
    const float4* xr = (const float4*)(x + (size_t)row * DIM) + lane * 2;
    const float4 a = xr[0];
    const float4 b = xr[1];
    float s = a.x * a.x + a.y * a.y + a.z * a.z + a.w * a.w
            + b.x * b.x + b.y * b.y + b.z * b.z + b.w * b.w;
    #pragma unroll
    for (int off = 1; off < 64; off <<= 1) s += __shfl_xor(s, off, 64);
    const float inv = 1.0f / sqrtf(s);
    const f16x8 h = { (_Float16)(a.x * inv), (_Float16)(a.y * inv),
                      (_Float16)(a.z * inv), (_Float16)(a.w * inv),
                      (_Float16)(b.x * inv), (_Float16)(b.y * inv),
                      (_Float16)(b.z * inv), (_Float16)(b.w * inv) };
    *(f16x8*)(xnh + (size_t)row * DIM + lane * 8) = h;

    if (blockIdx.x == 0 && threadIdx.x == 0) *out = 0.f;
}

// ---------------------------------------------------------------------------
// Kernel 2: TRIANGULAR Gram-tile GEMM + per-(row, 64-col-tile) top-3.
// Grid 64x64 flattened; blocks with J < I exit immediately (symmetry: each
// 128x128 tile pair computed once). Row-side harvest -> M3[rows of I][tiles
// of J]; col-side harvest (dot(i,j)=dot(j,i)) -> M3[rows of J][tiles of I].
// Diagonal tiles (I==J): row-side alone covers all 4 wave-quadrants.
// M3 layout: [row][jt2][3] floats, each slot written exactly once.
// ---------------------------------------------------------------------------
__global__ __launch_bounds__(256) void dots_top3_kernel(const _Float16* __restrict__ xnh,
                                                        float* __restrict__ M3) {
    const int I = blockIdx.x >> 6;       // row tile 0..63
    const int J = blockIdx.x & 63;       // col tile 0..63
    if (J < I) return;                   // uniform exit, before any barrier

    __shared__ __align__(16) _Float16 As[BM * BK];   // 8 KB
    __shared__ __align__(16) _Float16 Bs[BN * BK];   // 8 KB

    const int tid    = threadIdx.x;
    const int lane   = tid & 63;
    const int wv     = tid >> 6;
    const int wm     = wv >> 1;          // wave row half (0..1)
    const int wn     = wv & 1;           // wave col half (0..1)
    const int m_lane = lane & 15;        // MFMA: m (A) / n (B) / col (C)
    const int quad   = lane >> 4;        // MFMA: k-chunk (A,B) / row-group (C)

    const int i0 = I * BM;
    const int j0 = J * BN;

    // lane (quad, m_lane) owns row rowlocal (its (m,i) = (m_lane>>2, m_lane&3))
    const int rowlocal = (m_lane >> 2) * 16 + quad * 4 + (m_lane & 3);
    const int myrow    = i0 + wm * 64 + rowlocal;

    f32x4 acc[4][4];
    #pragma unroll
    for (int m = 0; m < 4; ++m)
        #pragma unroll
        for (int n = 0; n < 4; ++n)
            acc[m][n] = (f32x4){0.f, 0.f, 0.f, 0.f};

    for (int ks = 0; ks < DIM / BK; ++ks) {
        const int k0 = ks * BK;
        #pragma unroll
        for (int q = 0; q < 2; ++q) {
            const int s  = tid + q * 256;
            const int r  = s >> 2;
            const int kk = s & 3;
            gload16(xnh + (size_t)(i0 + r) * DIM + k0 + kk * 8, As + s * 8);
            gload16(xnh + (size_t)(j0 + r) * DIM + k0 + kk * 8, Bs + s * 8);
        }
        __syncthreads();

        f16x8 af[4], bf[4];
        #pragma unroll
        for (int m = 0; m < 4; ++m)
            af[m] = *(const f16x8*)(As + (wm * 64 + m * 16 + m_lane) * BK + quad * 8);
        #pragma unroll
        for (int n = 0; n < 4; ++n)
            bf[n] = *(const f16x8*)(Bs + (wn * 64 + n * 16 + m_lane) * BK + quad * 8);
        #pragma unroll
        for (int m = 0; m < 4; ++m)
            #pragma unroll
            for (int n = 0; n < 4; ++n)
                acc[m][n] = __builtin_amdgcn_mfma_f32_16x16x32_f16(af[m], bf[n], acc[m][n], 0, 0, 0);
        __syncthreads();
    }

    // diagonal mask: self-dot only when I==J && wm==wn && m==n.
    const bool diag = (I == J) && (wm == wn);
    #pragma unroll
    for (int m = 0; m < 4; ++m)
        #pragma unroll
        for (int i = 0; i < 4; ++i)
            acc[m][m][i] = (diag && (quad * 4 + i) == m_lane) ? -2.f : acc[m][m][i];

    // ---- row-side: per (m,i), top-3 of this row's 64 cols (butterfly) ----
    float g1 = -2.f, g2 = -2.f, g3 = -2.f;
    #pragma unroll
    for (int m = 0; m < 4; ++m) {
        #pragma unroll
        for (int i = 0; i < 4; ++i) {
            float v0 = acc[m][0][i], v1 = acc[m][1][i];
            float v2 = acc[m][2][i], v3 = acc[m][3][i];
            cmpswap(v0, v1); cmpswap(v2, v3);
            cmpswap(v0, v2); cmpswap(v1, v3);
            cmpswap(v1, v2);                     // v0>=v1>=v2 (>=v3, dropped)
            float a1 = v0, a2 = v1, a3 = v2;
            #pragma unroll
            for (int d = 1; d < 16; d <<= 1) {
                const float b1 = __shfl_xor(a1, d, 64);
                const float b2 = __shfl_xor(a2, d, 64);
                const float b3 = __shfl_xor(a3, d, 64);
                const float n1 = fmaxf(a1, b1);
                const float n2 = fmaxf(fminf(a1, b1), fmaxf(a2, b2));
                const float n3 = fmaxf(fmaxf(a3, b3),
                                       fmaxf(fminf(a1, b2), fminf(a2, b1)));
                a1 = n1; a2 = n2; a3 = n3;
            }
            const bool own = (m_lane == m * 4 + i);
            g1 = own ? a1 : g1; g2 = own ? a2 : g2; g3 = own ? a3 : g3;
        }
    }
    {
        float* p = M3 + ((size_t)myrow * NT64 + (J * 2 + wn)) * 3;
        p[0] = g1; p[1] = g2; p[2] = g3;
    }

    // ---- col-side (I != J): per n, top-3 of this col's 64 rows ----
    // lane-local insert3 over (m,i) [16 vals], then butterfly over quad
    // (lane bits 4,5 -> shfl_xor 16, 32). Column = j0 + wn*64 + n*16 + m_lane;
    // its 64-row range is tile index I*2 + wm.
    if (I != J) {
        #pragma unroll
        for (int n = 0; n < 4; ++n) {
            float c1 = -2.f, c2 = -2.f, c3 = -2.f;
            #pragma unroll
            for (int m = 0; m < 4; ++m)
                #pragma unroll
                for (int i = 0; i < 4; ++i) {
                    const float v  = acc[m][n][i];
                    const float u1 = fminf(c1, v);
                    c1 = fmaxf(c1, v);
                    const float u2 = fminf(c2, u1);
                    c2 = fmaxf(c2, u1);
                    c3 = fmaxf(c3, u2);
                }
            #pragma unroll
            for (int d = 16; d < 64; d <<= 1) {
                const float b1 = __shfl_xor(c1, d, 64);
                const float b2 = __shfl_xor(c2, d, 64);
                const float b3 = __shfl_xor(c3, d, 64);
                const float n2 = fmaxf(fminf(c1, b1), fmaxf(c2, b2));
                const float n3 = fmaxf(fmaxf(c3, b3),
                                       fmaxf(fminf(c1, b2), fminf(c2, b1)));
                c1 = fmaxf(c1, b1); c2 = n2; c3 = n3;
            }
            if (quad == 0) {
                const int col = j0 + wn * 64 + n * 16 + m_lane;
                float* p = M3 + ((size_t)col * NT64 + (I * 2 + wm)) * 3;
                p[0] = c1; p[1] = c2; p[2] = c3;
            }
        }
    }
}

// ---------------------------------------------------------------------------
// Kernel 3: exact top-5 per row from the 128 stored triples + loss.
// One wave per row. Pool ⊆ full set ⇒ pool's t[4] ≤ true 5th-best; a tile can
// hide a missed value only if its stored 3rd ≥ t[4] — exactly recompute those.
// ---------------------------------------------------------------------------
__global__ __launch_bounds__(256) void select_loss_kernel(const _Float16* __restrict__ xnh,
                                                          const float* __restrict__ M3,
                                                          float* __restrict__ out) {
    const int wv = threadIdx.x >> 6, lane = threadIdx.x & 63;
    const int row = blockIdx.x * 4 + wv;
    const float* p = M3 + (size_t)row * NT64 * 3 + lane * 6;
    float a[3], b[3];
    a[0] = p[0]; a[1] = p[1]; a[2] = p[2];
    b[0] = p[3]; b[1] = p[4]; b[2] = p[5];

    float t[KNN];
    {
        float c[KNN] = { a[0], a[1], a[2], -2.f, -2.f };
        const float bb[KNN] = { b[0], b[1], b[2], -2.f, -2.f };
        merge5(c, bb);
        #pragma unroll
        for (int d = 1; d < 64; d <<= 1) {
            float o[KNN];
            #pragma unroll
            for (int k = 0; k < KNN; ++k) o[k] = __shfl_xor(c[k], d, 64);
            merge5(c, o);
        }
        #pragma unroll
        for (int k = 0; k < KNN; ++k) t[k] = c[k];
    }

    // flag tiles whose stored 3rd could hide a missed top-5 value
    const unsigned long long ba = __ballot(a[2] >= t[4]);
    const unsigned long long bb_ = __ballot(b[2] >= t[4]);
    if (ba | bb_) {
        // rebuild the pool top-5 excluding flagged tiles
        const bool fA = (ba >> lane) & 1ull, fB = (bb_ >> lane) & 1ull;
        float c[KNN] = { fA ? -2.f : a[0], fA ? -2.f : a[1], fA ? -2.f : a[2],
                         -2.f, -2.f };
        const float b5[KNN] = { fB ? -2.f : b[0], fB ? -2.f : b[1],
                                fB ? -2.f : b[2], -2.f, -2.f };
        merge5(c, b5);
        #pragma unroll
        for (int d = 1; d < 64; d <<= 1) {
            float o[KNN];
            #pragma unroll
            for (int k = 0; k < KNN; ++k) o[k] = __shfl_xor(c[k], d, 64);
            merge5(c, o);
        }
        #pragma unroll
        for (int k = 0; k < KNN; ++k) t[k] = c[k];

        // exactly recompute each flagged 64-col tile (whole wave, 1 col/lane)
        unsigned long long fl[2] = { ba, bb_ };
        #pragma unroll
        for (int h = 0; h < 2; ++h) {
            unsigned long long m = fl[h];
            while (m) {
                const int l = __ffsll((long long)m) - 1;
                m &= m - 1;
                const int jt2 = 2 * l + h;
                const int col = jt2 * 64 + lane;
                const _Float16* rp = xnh + (size_t)row * DIM;
                const _Float16* cp = xnh + (size_t)col * DIM;
                float d = 0.f;
                for (int k8 = 0; k8 < DIM / 8; ++k8) {
                    const f16x8 rv = *(const f16x8*)(rp + k8 * 8);
                    const f16x8 cv = *(const f16x8*)(cp + k8 * 8);
                    #pragma unroll
                    for (int e = 0; e < 8; ++e)
                        d += (float)rv[e] * (float)cv[e];
                }
                if (col == row) d = -2.f;
                float c2[KNN] = { d, -2.f, -2.f, -2.f, -2.f };
                #pragma unroll
                for (int dd = 1; dd < 64; dd <<= 1) {
                    float o[KNN];
                    #pragma unroll
                    for (int k = 0; k < KNN; ++k) o[k] = __shfl_xor(c2[k], dd, 64);
                    merge5(c2, o);
                }
                merge5(t, c2);
            }
        }
    }

    // loss: unit vectors -> dist_k = sqrt(2 - 2*dot_k)
    float s = 0.f;
    #pragma unroll
    for (int k = 0; k < KNN; ++k) s += sqrtf(fmaxf(2.f - 2.f * t[k], 0.f));
    const float val = logf(s * (1.f / KNN) + EPSV);

    __shared__ float red[4];
    if (lane == 0) red[wv] = val;
    __syncthreads();
    if (threadIdx.x == 0) {
        const float blocksum = red[0] + red[1] + red[2] + red[3];
        atomicAdd(out, -blocksum / (float)NROWS);
    }
}

// ---------------------------------------------------------------------------
extern "C" void kernel_launch(void* const* d_in, const int* in_sizes, int n_in,
                              void* d_out, int out_size, void* d_ws, size_t ws_size,
                              hipStream_t stream) {
    const float* x = (const float*)d_in[0];
    float* out = (float*)d_out;
    char* ws = (char*)d_ws;

    _Float16* xnh = (_Float16*)ws;                                     // 8 MB
    float* M3 = (float*)(ws + (size_t)NROWS * DIM * sizeof(_Float16)); // 12.6 MB

    norm_kernel<<<NROWS / 4, 256, 0, stream>>>(x, xnh, out);
    dots_top3_kernel<<<NT * NT, 256, 0, stream>>>(xnh, M3);
    select_loss_kernel<<<NROWS / 4, 256, 0, stream>>>(xnh, M3, out);
}